// Round 11
// baseline (206.348 us; speedup 1.0000x reference)
//
#include <hip/hip_runtime.h>

#define N_SIG 2048
#define NT    32             // 2048/64 tiles per dimension
#define N_PAIR_BLOCKS 2048   // 496 off-diag tiles*4 quarters + 32 diag tiles*2 halves

__device__ __forceinline__ float frcp(float x) { return __builtin_amdgcn_rcpf(x); }

// erf(y / sqrt(2)) — Abramowitz–Stegun 7.1.26 with sqrt2 folded in, |err| < 1.5e-7
__device__ __forceinline__ float erf_div_sqrt2(float y) {
    const float ay = fabsf(y);
    const float t  = frcp(fmaf(0.23164454f, ay, 1.f));   // p/sqrt2, p = 0.3275911
    const float p  = t * fmaf(t, fmaf(t, fmaf(t, fmaf(t, 1.061405429f, -1.453152027f),
                                              1.421413741f), -0.284496736f), 0.254829592f);
    const float e  = __expf(-0.5f * ay * ay);
    return copysignf(fmaf(-p, e, 1.f), y);
}

// ---------------- Kernel 1: per-signal derived quantities + zero acc ----------------
__global__ void derive_k(const float* __restrict__ p, float* __restrict__ dv,
                         float* __restrict__ acc) {
    int j = blockIdx.x * blockDim.x + threadIdx.x;
    if (j >= N_SIG) return;
    #pragma unroll
    for (int k = 0; k < 9; k++) acc[j * 9 + k] = 0.f;
    const float* pj = p + j * 15;
    float m1 = pj[0] * 95.f + 5.f, m2 = pj[1] * 95.f + 5.f;
    float mc = powf(m1 * m2, 0.6f) / powf(m1 + m2, 0.2f);
    float fisco = 220.f / (m1 + m2);
    float dist = pj[2] * 2950.f + 50.f;
    float4* o = (float4*)(dv + j * 8);
    o[0] = make_float4(pj[5], pj[3], pj[4], mc);   // t, ra, dec, mc
    o[1] = make_float4(fisco, dist, pj[7], 0.f);   // fisco, dist, psi, pad
}

// ---------------- Kernel 2: symmetric pair tiles, grid-filled ----------------
// r10 analysis: hot loop fine (weights via s_load/SMEM, ec[] uniform, LDS pipe
// quiet) but grid of 1056 blocks = 270K threads only half-fills the device
// (~4 waves/SIMD resident). r11: off-diag tiles split 4-ways -> 2048 blocks,
// 6 waves/SIMD resident at VGPR=76. Hot loop unchanged from r10.
// NOTE: plain __launch_bounds__(256) — a min-waves arg caps VGPR and causes
// catastrophic scratch spills (rounds 5/6: 1.1 GB HBM spill traffic).
__global__ __launch_bounds__(256) void pair_k(
    const float* __restrict__ dv,
    const float* __restrict__ iw1, const float* __restrict__ ib1,
    const float* __restrict__ ig1, const float* __restrict__ ibt1,
    const float* __restrict__ iw2,
    float* __restrict__ acc)
{
    __shared__ float4 sColA[64], sColB[64];    // column-group signals
    __shared__ __align__(16) float sEC[64];    // per-h (b1, g1, bt1, 0.5*w2) staging
    __shared__ float part[9 * 256];            // [q][wave*64+idx], two-phase reuse

    // ---- tile decode: off-diag quarters first, half-work diag halves last ----
    const int b = blockIdx.x;
    const int tid = threadIdx.x;
    const int w = tid >> 6, l = tid & 63;

    int ti, tj, U;            // U = virtual-wave index within the tile
    bool diag;
    if (b < 1984) {
        int k = b >> 2;       // off-diag tile id 0..495
        ti = 0;
        int cnt = NT - 1;
        while (k >= cnt) { k -= cnt; ti++; cnt = NT - 1 - ti; }
        tj = ti + 1 + k;
        U = (b & 3) * 4 + w;  // 0..15, each covers s in [4U, 4U+3]
        diag = false;
    } else {
        const int d = b - 1984;
        ti = tj = d >> 1;
        U = (d & 1) * 4 + w;  // 0..7, covers s in [4U+1, 4U+4]
        diag = true;
    }
    const int rbase = ti * 64, cbase = tj * 64;

    const float4* dv4 = (const float4*)dv;

    if (tid < 64) { sColA[tid] = dv4[(cbase + tid) * 2]; sColB[tid] = dv4[(cbase + tid) * 2 + 1]; }
    if (tid >= 192 && tid < 208) {
        int h = tid - 192;
        sEC[h * 4 + 0] = ib1[h]; sEC[h * 4 + 1] = ig1[h];
        sEC[h * 4 + 2] = ibt1[h]; sEC[h * 4 + 3] = 0.5f * iw2[h];
    }
    __syncthreads();

    // epilogue constants (uniform; compiler scalarizes)
    float4 ec[16];
    #pragma unroll
    for (int h = 0; h < 16; h++) ec[h] = ((const float4*)sEC)[h];

    const int gi = rbase + l;
    const float4 r0 = dv4[gi * 2], r1 = dv4[gi * 2 + 1];
    const float ti_ = r0.x, rai = r0.y, deci = r0.z, mci = r0.w;
    const float fi = r1.x, disti = r1.y, psii = r1.z;

    const int iters = 2;
    const int s0 = diag ? (U * 4 + 1) : (U * 4);

    float rowacc[9], colacc[9];
    #pragma unroll
    for (int q = 0; q < 9; q++) { rowacc[q] = 0.f; colacc[q] = 0.f; }

    const int rotm1 = (l + 63) & 63;   // pull from lane l-1
    const int rot2  = (l + 2) & 63;    // frame rotation by +2

    #pragma unroll 1
    for (int t = 0; t < iters; t++) {
        const int sA = s0 + 2 * t, sB = sA + 1;
        const int djA = (l + sA) & 63, djB = (l + sB) & 63;
        const float4 a0 = sColA[djA], a1 = sColB[djA];
        const float4 b0 = sColA[djB], b1 = sColB[djB];

        // ---- symmetric pairwise features, 2 independent chains ----
        const float draA = fabsf(rai - a0.y), ddecA = fabsf(deci - a0.z);
        const float draB = fabsf(rai - b0.y), ddecB = fabsf(deci - b0.z);
        float fA[8], fB[8];
        fA[0] = fabsf(ti_ - a0.x);
        fA[1] = __builtin_amdgcn_sqrtf(fmaf(draA, draA, ddecA * ddecA));
        fA[2] = frcp(fmaf(fabsf(mci - a0.w), 0.033333333f, 1.f));
        fA[3] = __expf(fabsf(fi - a1.x) * -0.01f);
        fA[4] = fminf(disti, a1.y) * frcp(fmaxf(disti, a1.y));
        fA[5] = fabsf(psii - a1.z);
        fA[6] = draA; fA[7] = ddecA;
        fB[0] = fabsf(ti_ - b0.x);
        fB[1] = __builtin_amdgcn_sqrtf(fmaf(draB, draB, ddecB * ddecB));
        fB[2] = frcp(fmaf(fabsf(mci - b0.w), 0.033333333f, 1.f));
        fB[3] = __expf(fabsf(fi - b1.x) * -0.01f);
        fB[4] = fminf(disti, b1.y) * frcp(fmaxf(disti, b1.y));
        fB[5] = fabsf(psii - b1.z);
        fB[6] = draB; fB[7] = ddecB;

        // ---- 8->16 GEMV: weights via wave-uniform GLOBAL loads (s_load) ----
        float zA[16], zB[16];
        float s1A = 0.f, s2A = 0.f, s1B = 0.f, s2B = 0.f;
        #pragma unroll
        for (int h = 0; h < 16; h++) {
            const float* wr = iw1 + h * 8;   // uniform, loop-invariant -> SGPR
            const float bh = ec[h].x;
            float za = bh, zb = bh;
            #pragma unroll
            for (int q = 0; q < 8; q++) {
                const float wq = wr[q];
                za = fmaf(wq, fA[q], za);
                zb = fmaf(wq, fB[q], zb);
            }
            zA[h] = za; zB[h] = zb;
            s1A += za; s2A = fmaf(za, za, s2A);
            s1B += zb; s2B = fmaf(zb, zb, s2B);
        }
        const float muA  = s1A * 0.0625f;
        const float invA = __builtin_amdgcn_rsqf(fmaf(-muA, muA, s2A * 0.0625f) + 1e-5f);
        const float muB  = s1B * 0.0625f;
        const float invB = __builtin_amdgcn_rsqf(fmaf(-muB, muB, s2B * 0.0625f) + 1e-5f);

        // ---- GELU(erf) + dot(iw2), 2 chains ----
        float logitA = 0.f, logitB = 0.f;
        #pragma unroll
        for (int h = 0; h < 16; h++) {
            const float4 c = ec[h];  // (b, g, bt, 0.5*w2)
            const float yA = fmaf((zA[h] - muA) * invA, c.y, c.z);
            const float yB = fmaf((zB[h] - muB) * invB, c.y, c.z);
            logitA = fmaf(yA * c.w, 1.f + erf_div_sqrt2(yA), logitA);
            logitB = fmaf(yB * c.w, 1.f + erf_div_sqrt2(yB), logitB);
        }
        const float eA = __expf(logitA);
        float eB = __expf(logitB);
        // diag tile: s=32 pairs appear twice (lane l / lane l^32) -> keep half
        if (diag && sB == 32 && l >= 32) eB = 0.f;

        // ---- row accumulation (lane-fixed, both pairs direct) ----
        rowacc[8] += eA + eB;
        #pragma unroll
        for (int q = 0; q < 8; q++)
            rowacc[q] = fmaf(eA, fA[q], fmaf(eB, fB[q], rowacc[q]));

        // ---- col accumulation: A direct; B shifted one lane into A's frame ----
        float prodB[9];
        #pragma unroll
        for (int q = 0; q < 8; q++) prodB[q] = eB * fB[q];
        prodB[8] = eB;
        colacc[8] += eA + __shfl(prodB[8], rotm1);
        #pragma unroll
        for (int q = 0; q < 8; q++)
            colacc[q] = fmaf(eA, fA[q], colacc[q] + __shfl(prodB[q], rotm1));

        // rotate col frame: next iteration's sA is +2
        if (t + 1 < iters) {
            #pragma unroll
            for (int q = 0; q < 9; q++) colacc[q] = __shfl(colacc[q], rot2);
        }
    }

    const int stag = b & 63;  // stagger scatter start to decorrelate blocks

    // ---- phase 1: row side (lane l owns row l) ----
    #pragma unroll
    for (int q = 0; q < 9; q++) part[q * 256 + w * 64 + l] = rowacc[q];
    __syncthreads();
    if (tid < 192) {
        const int sig = (tid + stag) & 63;
        const int qb = (tid >> 6) * 3;
        #pragma unroll
        for (int r = 0; r < 3; r++) {
            const int q = qb + r;
            const float* pp = part + q * 256 + sig;
            unsafeAtomicAdd(&acc[(rbase + sig) * 9 + q], pp[0] + pp[64] + pp[128] + pp[192]);
        }
    }
    __syncthreads();

    // ---- phase 2: col side (un-rotate to true column index) ----
    const int s_last = s0 + 2 * (iters - 1);
    const int cfin = (l + s_last) & 63;
    #pragma unroll
    for (int q = 0; q < 9; q++) part[q * 256 + w * 64 + cfin] = colacc[q];
    __syncthreads();
    if (tid < 192) {
        const int sig = (tid + stag) & 63;
        const int qb = (tid >> 6) * 3;
        #pragma unroll
        for (int r = 0; r < 3; r++) {
            const int q = qb + r;
            const float* pp = part + q * 256 + sig;
            unsafeAtomicAdd(&acc[(cbase + sig) * 9 + q], pp[0] + pp[64] + pp[128] + pp[192]);
        }
    }
}

// ---------------- Kernel 3: overlap net per row ----------------
__global__ void out_k(const float* __restrict__ acc,
                      const float* __restrict__ ow1, const float* __restrict__ ob1,
                      const float* __restrict__ og1, const float* __restrict__ obt1,
                      const float* __restrict__ ow2, const float* __restrict__ ob2,
                      float* __restrict__ out)
{
    __shared__ float h2s[32];
    const int i = blockIdx.x, t = threadIdx.x;   // 64 threads
    if (t < 32) {
        const float invL = frcp(acc[i * 9 + 8]);
        float z2 = ob1[t];
        #pragma unroll
        for (int f = 0; f < 8; f++) z2 = fmaf(ow1[t * 8 + f], acc[i * 9 + f] * invL, z2);
        float mu = z2;
        #pragma unroll
        for (int off = 16; off > 0; off >>= 1) mu += __shfl_xor(mu, off);
        mu *= (1.f / 32.f);
        const float d = z2 - mu;
        float var = d * d;
        #pragma unroll
        for (int off = 16; off > 0; off >>= 1) var += __shfl_xor(var, off);
        var *= (1.f / 32.f);
        const float y = d * __builtin_amdgcn_rsqf(var + 1e-5f) * og1[t] + obt1[t];
        h2s[t] = 0.5f * y * (1.f + erf_div_sqrt2(y));
    }
    __syncthreads();
    if (t < 16) {
        float o = ob2[t];
        #pragma unroll
        for (int k = 0; k < 32; k++) o = fmaf(ow2[t * 32 + k], h2s[k], o);
        out[i * 16 + t] = o;
    }
}

extern "C" void kernel_launch(void* const* d_in, const int* in_sizes, int n_in,
                              void* d_out, int out_size, void* d_ws, size_t ws_size,
                              hipStream_t stream) {
    const float* p    = (const float*)d_in[0];
    const float* iw1  = (const float*)d_in[1];
    const float* ib1  = (const float*)d_in[2];
    const float* ig1  = (const float*)d_in[3];
    const float* ibt1 = (const float*)d_in[4];
    const float* iw2  = (const float*)d_in[5];
    // d_in[6] = ib2: uniform logit offset, softmax-invariant -> unused
    const float* ow1  = (const float*)d_in[7];
    const float* ob1  = (const float*)d_in[8];
    const float* og1  = (const float*)d_in[9];
    const float* obt1 = (const float*)d_in[10];
    const float* ow2  = (const float*)d_in[11];
    const float* ob2  = (const float*)d_in[12];

    float* dv  = (float*)d_ws;                 // [2048][8]
    float* acc = (float*)d_ws + N_SIG * 8;     // [2048][9] (sum e*f, sum e)

    derive_k<<<N_SIG / 256, 256, 0, stream>>>(p, dv, acc);
    pair_k<<<N_PAIR_BLOCKS, 256, 0, stream>>>(dv, iw1, ib1, ig1, ibt1, iw2, acc);
    out_k<<<N_SIG, 64, 0, stream>>>(acc, ow1, ob1, og1, obt1, ow2, ob2,
                                    (float*)d_out);
}

// Round 12
// 151.617 us; speedup vs baseline: 1.3610x; 1.3610x over previous
//
#include <hip/hip_runtime.h>

#define N_SIG 2048
#define NT    32           // 2048/64 tiles per dimension
#define N_PAIR_BLOCKS 1056 // 496 off-diag tiles*2 halves + 32 diag tiles*2 halves

typedef float v2f __attribute__((ext_vector_type(2)));

__device__ __forceinline__ float frcp(float x) { return __builtin_amdgcn_rcpf(x); }
__device__ __forceinline__ v2f splat2(float s) { v2f r; r.x = s; r.y = s; return r; }
__device__ __forceinline__ v2f pkfma(v2f a, v2f b, v2f c) {
#if __has_builtin(__builtin_elementwise_fma)
    return __builtin_elementwise_fma(a, b, c);
#else
    v2f r; r.x = fmaf(a.x, b.x, c.x); r.y = fmaf(a.y, b.y, c.y); return r;
#endif
}
__device__ __forceinline__ v2f pkabs(v2f a) {
#if __has_builtin(__builtin_elementwise_abs)
    return __builtin_elementwise_abs(a);
#else
    v2f r; r.x = fabsf(a.x); r.y = fabsf(a.y); return r;
#endif
}

// packed erf(y/sqrt2) — A&S 7.1.26, sqrt2 folded; poly packed, rcp/exp scalar
__device__ __forceinline__ v2f erf2(v2f y) {
    const v2f ay = pkabs(y);
    v2f t;
    t.x = frcp(fmaf(0.23164454f, ay.x, 1.f));
    t.y = frcp(fmaf(0.23164454f, ay.y, 1.f));
    v2f p = pkfma(t, splat2(1.061405429f), splat2(-1.453152027f));
    p = pkfma(t, p, splat2(1.421413741f));
    p = pkfma(t, p, splat2(-0.284496736f));
    p = pkfma(t, p, splat2(0.254829592f));
    p = t * p;
    const v2f narg = (ay * ay) * splat2(-0.5f);
    v2f e;
    e.x = __expf(narg.x); e.y = __expf(narg.y);
    v2f r = pkfma(-p, e, splat2(1.f));
    r.x = copysignf(r.x, y.x); r.y = copysignf(r.y, y.y);
    return r;
}

// ---------------- Kernel 1: per-signal derived quantities + zero acc ----------------
__global__ void derive_k(const float* __restrict__ p, float* __restrict__ dv,
                         float* __restrict__ acc) {
    int j = blockIdx.x * blockDim.x + threadIdx.x;
    if (j >= N_SIG) return;
    #pragma unroll
    for (int k = 0; k < 9; k++) acc[j * 9 + k] = 0.f;
    const float* pj = p + j * 15;
    float m1 = pj[0] * 95.f + 5.f, m2 = pj[1] * 95.f + 5.f;
    float mc = powf(m1 * m2, 0.6f) / powf(m1 + m2, 0.2f);
    float fisco = 220.f / (m1 + m2);
    float dist = pj[2] * 2950.f + 50.f;
    float4* o = (float4*)(dv + j * 8);
    o[0] = make_float4(pj[5], pj[3], pj[4], mc);   // t, ra, dec, mc
    o[1] = make_float4(fisco, dist, pj[7], 0.f);   // fisco, dist, psi, pad
}

// ---------------- Kernel 2: symmetric pair tiles, packed-fp32 dual chains ----------------
// r11 lesson: 1056 blocks (not 2048) — per-block fixed costs dominate short loops.
// r10 lesson: weights/consts via wave-uniform global s_loads keep the LDS pipe quiet.
// r12: A/B pair chains packed into v2f -> v_pk_fma_f32 halves the fma slot count.
// NOTE: plain __launch_bounds__(256) — a min-waves arg caps VGPR and causes
// catastrophic scratch spills (rounds 5/6: 1.1 GB HBM spill traffic).
__global__ __launch_bounds__(256) void pair_k(
    const float* __restrict__ dv,
    const float* __restrict__ iw1, const float* __restrict__ ib1,
    const float* __restrict__ ig1, const float* __restrict__ ibt1,
    const float* __restrict__ iw2,
    float* __restrict__ acc)
{
    __shared__ float4 sColA[64], sColB[64];    // column-group signals
    __shared__ float part[9 * 256];            // [q][wave*64+idx], two-phase reuse

    // ---- tile decode: off-diag halves first, half-work diag halves last ----
    const int b = blockIdx.x;
    const int tid = threadIdx.x;
    const int w = tid >> 6, l = tid & 63;

    int ti, tj;
    bool diag;
    if (b < 992) {
        int k = b >> 1;
        ti = 0;
        int cnt = NT - 1;
        while (k >= cnt) { k -= cnt; ti++; cnt = NT - 1 - ti; }
        tj = ti + 1 + k;
        diag = false;
    } else {
        ti = tj = (b - 992) >> 1;
        diag = true;
    }
    const int half = b & 1;
    const int V = half * 4 + w;          // virtual wave 0..7
    const int rbase = ti * 64, cbase = tj * 64;

    const float4* dv4 = (const float4*)dv;

    if (tid < 64) { sColA[tid] = dv4[(cbase + tid) * 2]; sColB[tid] = dv4[(cbase + tid) * 2 + 1]; }
    __syncthreads();

    const int gi = rbase + l;
    const float4 r0 = dv4[gi * 2], r1 = dv4[gi * 2 + 1];
    const float ti_ = r0.x, rai = r0.y, deci = r0.z, mci = r0.w;
    const float fi = r1.x, disti = r1.y, psii = r1.z;

    // offset spans: off-diag V covers s in [8V, 8V+7]; diag [4V+1, 4V+4]
    const int iters = diag ? 2 : 4;
    const int s0    = diag ? (V * 4 + 1) : (V * 8);

    v2f rowacc2[9];
    float colacc[9];
    #pragma unroll
    for (int q = 0; q < 9; q++) { rowacc2[q] = splat2(0.f); colacc[q] = 0.f; }

    const int rotm1 = (l + 63) & 63;   // pull from lane l-1
    const int rot2  = (l + 2) & 63;    // frame rotation by +2

    #pragma unroll 1
    for (int t = 0; t < iters; t++) {
        const int sA = s0 + 2 * t, sB = sA + 1;
        const int djA = (l + sA) & 63, djB = (l + sB) & 63;
        const float4 a0 = sColA[djA], a1 = sColB[djA];
        const float4 b0 = sColA[djB], b1 = sColB[djB];

        // pack pair A (.x) and pair B (.y)
        const v2f c0x = {a0.x, b0.x}, c0y = {a0.y, b0.y}, c0z = {a0.z, b0.z}, c0w = {a0.w, b0.w};
        const v2f c1x = {a1.x, b1.x}, c1y = {a1.y, b1.y}, c1z = {a1.z, b1.z};

        // ---- symmetric pairwise features (packed) ----
        const v2f dra  = pkabs(splat2(rai) - c0y);
        const v2f ddec = pkabs(splat2(deci) - c0z);
        v2f f[8];
        f[0] = pkabs(splat2(ti_) - c0x);
        {
            const v2f ss = pkfma(dra, dra, ddec * ddec);
            f[1].x = __builtin_amdgcn_sqrtf(ss.x);
            f[1].y = __builtin_amdgcn_sqrtf(ss.y);
        }
        {
            const v2f den = pkfma(pkabs(splat2(mci) - c0w), splat2(0.033333333f), splat2(1.f));
            f[2].x = frcp(den.x); f[2].y = frcp(den.y);
        }
        {
            const v2f fd = pkabs(splat2(fi) - c1x) * splat2(-0.01f);
            f[3].x = __expf(fd.x); f[3].y = __expf(fd.y);
        }
        {
            const v2f di = splat2(disti);
            v2f mn, mx;
            mn.x = fminf(di.x, c1y.x); mn.y = fminf(di.y, c1y.y);
            mx.x = fmaxf(di.x, c1y.x); mx.y = fmaxf(di.y, c1y.y);
            v2f rcpmx; rcpmx.x = frcp(mx.x); rcpmx.y = frcp(mx.y);
            f[4] = mn * rcpmx;
        }
        f[5] = pkabs(splat2(psii) - c1z);
        f[6] = dra; f[7] = ddec;

        // ---- 8->16 GEMV: weights via wave-uniform global s_loads; packed fma ----
        v2f z2[16];
        v2f s1 = splat2(0.f), s2 = splat2(0.f);
        #pragma unroll
        for (int h = 0; h < 16; h++) {
            const float* wr = iw1 + h * 8;   // uniform, loop-invariant -> SGPR
            v2f z = splat2(ib1[h]);
            #pragma unroll
            for (int q = 0; q < 8; q++) z = pkfma(splat2(wr[q]), f[q], z);
            z2[h] = z;
            s1 = s1 + z;
            s2 = pkfma(z, z, s2);
        }
        const v2f mu  = s1 * splat2(0.0625f);
        const v2f var = pkfma(-mu, mu, s2 * splat2(0.0625f));
        v2f inv;
        inv.x = __builtin_amdgcn_rsqf(var.x + 1e-5f);
        inv.y = __builtin_amdgcn_rsqf(var.y + 1e-5f);

        // ---- GELU(erf) + dot(iw2), packed ----
        v2f logit = splat2(0.f);
        #pragma unroll
        for (int h = 0; h < 16; h++) {
            const v2f y = pkfma((z2[h] - mu) * inv, splat2(ig1[h]), splat2(ibt1[h]));
            const v2f er = erf2(y);
            logit = pkfma(y * splat2(0.5f * iw2[h]), splat2(1.f) + er, logit);
        }
        const float eA = __expf(logit.x);
        float eB = __expf(logit.y);
        // diag tile: s=32 pairs appear twice (lane l / lane l^32) -> keep half
        if (diag && sB == 32 && l >= 32) eB = 0.f;
        v2f e2; e2.x = eA; e2.y = eB;

        // ---- row accumulation (packed); col: A direct + B shifted one lane ----
        rowacc2[8] = rowacc2[8] + e2;
        colacc[8] += eA + __shfl(eB, rotm1);
        #pragma unroll
        for (int q = 0; q < 8; q++) {
            const v2f pr = e2 * f[q];
            rowacc2[q] = rowacc2[q] + pr;
            colacc[q] += pr.x + __shfl(pr.y, rotm1);
        }
        // rotate col frame: next iteration's sA is +2
        if (t + 1 < iters) {
            #pragma unroll
            for (int q = 0; q < 9; q++) colacc[q] = __shfl(colacc[q], rot2);
        }
    }

    const int stag = b & 63;  // stagger scatter start to decorrelate blocks

    // ---- phase 1: row side (lane l owns row l) ----
    #pragma unroll
    for (int q = 0; q < 9; q++) part[q * 256 + w * 64 + l] = rowacc2[q].x + rowacc2[q].y;
    __syncthreads();
    if (tid < 192) {
        const int sig = (tid + stag) & 63;
        const int qb = (tid >> 6) * 3;
        #pragma unroll
        for (int r = 0; r < 3; r++) {
            const int q = qb + r;
            const float* pp = part + q * 256 + sig;
            unsafeAtomicAdd(&acc[(rbase + sig) * 9 + q], pp[0] + pp[64] + pp[128] + pp[192]);
        }
    }
    __syncthreads();

    // ---- phase 2: col side (un-rotate to true column index) ----
    const int s_last = s0 + 2 * (iters - 1);
    const int cfin = (l + s_last) & 63;
    #pragma unroll
    for (int q = 0; q < 9; q++) part[q * 256 + w * 64 + cfin] = colacc[q];
    __syncthreads();
    if (tid < 192) {
        const int sig = (tid + stag) & 63;
        const int qb = (tid >> 6) * 3;
        #pragma unroll
        for (int r = 0; r < 3; r++) {
            const int q = qb + r;
            const float* pp = part + q * 256 + sig;
            unsafeAtomicAdd(&acc[(cbase + sig) * 9 + q], pp[0] + pp[64] + pp[128] + pp[192]);
        }
    }
}

// ---------------- Kernel 3: overlap net per row ----------------
__global__ void out_k(const float* __restrict__ acc,
                      const float* __restrict__ ow1, const float* __restrict__ ob1,
                      const float* __restrict__ og1, const float* __restrict__ obt1,
                      const float* __restrict__ ow2, const float* __restrict__ ob2,
                      float* __restrict__ out)
{
    __shared__ float h2s[32];
    const int i = blockIdx.x, t = threadIdx.x;   // 64 threads
    if (t < 32) {
        const float invL = frcp(acc[i * 9 + 8]);
        float z2 = ob1[t];
        #pragma unroll
        for (int f = 0; f < 8; f++) z2 = fmaf(ow1[t * 8 + f], acc[i * 9 + f] * invL, z2);
        float mu = z2;
        #pragma unroll
        for (int off = 16; off > 0; off >>= 1) mu += __shfl_xor(mu, off);
        mu *= (1.f / 32.f);
        const float d = z2 - mu;
        float var = d * d;
        #pragma unroll
        for (int off = 16; off > 0; off >>= 1) var += __shfl_xor(var, off);
        var *= (1.f / 32.f);
        const float yv = d * __builtin_amdgcn_rsqf(var + 1e-5f) * og1[t] + obt1[t];
        const float ay = fabsf(yv);
        const float tt = frcp(fmaf(0.23164454f, ay, 1.f));
        const float pp = tt * fmaf(tt, fmaf(tt, fmaf(tt, fmaf(tt, 1.061405429f, -1.453152027f),
                                                     1.421413741f), -0.284496736f), 0.254829592f);
        const float ee = __expf(-0.5f * ay * ay);
        const float er = copysignf(fmaf(-pp, ee, 1.f), yv);
        h2s[t] = 0.5f * yv * (1.f + er);
    }
    __syncthreads();
    if (t < 16) {
        float o = ob2[t];
        #pragma unroll
        for (int k = 0; k < 32; k++) o = fmaf(ow2[t * 32 + k], h2s[k], o);
        out[i * 16 + t] = o;
    }
}

extern "C" void kernel_launch(void* const* d_in, const int* in_sizes, int n_in,
                              void* d_out, int out_size, void* d_ws, size_t ws_size,
                              hipStream_t stream) {
    const float* p    = (const float*)d_in[0];
    const float* iw1  = (const float*)d_in[1];
    const float* ib1  = (const float*)d_in[2];
    const float* ig1  = (const float*)d_in[3];
    const float* ibt1 = (const float*)d_in[4];
    const float* iw2  = (const float*)d_in[5];
    // d_in[6] = ib2: uniform logit offset, softmax-invariant -> unused
    const float* ow1  = (const float*)d_in[7];
    const float* ob1  = (const float*)d_in[8];
    const float* og1  = (const float*)d_in[9];
    const float* obt1 = (const float*)d_in[10];
    const float* ow2  = (const float*)d_in[11];
    const float* ob2  = (const float*)d_in[12];

    float* dv  = (float*)d_ws;                 // [2048][8]
    float* acc = (float*)d_ws + N_SIG * 8;     // [2048][9] (sum e*f, sum e)

    derive_k<<<N_SIG / 256, 256, 0, stream>>>(p, dv, acc);
    pair_k<<<N_PAIR_BLOCKS, 256, 0, stream>>>(dv, iw1, ib1, ig1, ibt1, iw2, acc);
    out_k<<<N_SIG, 64, 0, stream>>>(acc, ow1, ob1, og1, obt1, ow2, ob2,
                                    (float*)d_out);
}